// Round 7
// baseline (222.219 us; speedup 1.0000x reference)
//
#include <hip/hip_runtime.h>
#include <hip/hip_cooperative_groups.h>
#include <math.h>

namespace cg = cooperative_groups;

#define NBATCH 16
#define NATOM  512
#define NEIGH  64
#define PPM    (NATOM * NEIGH)      // 32768 = 2^15
#define NPAIR  (NBATCH * PPM)       // 524288
#define TOTATOM (NBATCH * NATOM)    // 8192
#define NTYPE  4
#define NWAVE  8
#define MAXN   128                  // slot capacity per atom (avg 64; Poisson tail safe at 128)

typedef float nfloat4 __attribute__((ext_vector_type(4)));

// ---- workspace layout (bytes) ----
// cursors : int[8192]                      @ 0        (32 KB)
// records : float4[TOTATOM * MAXN] (16 MB) @ 32768
#define WS_OFF_RECORDS 32768

// Single cooperative kernel: {zero cursors} -> grid.sync -> {scatter} ->
// grid.sync -> {density}. Replaces 3 dispatches (R6: zero+scatter+density)
// to remove 2 launch boundaries + the zero kernel's dispatch overhead.
// Grid = 1024 blocks x 256 thr: needs 4 blocks/CU co-resident, guaranteed
// by __launch_bounds__(256,4) (VGPR <= 128; density uses ~40).
//
// Kept from earlier rounds (measured):
//  - plain stores (nt regressed ~4us, R3/R4: random 16B stores must L2-merge)
//  - no XCD swizzle (regressed ~4.5us, R5)
//  - native v_cos_f32/v_exp_f32 (won ~1us, R6; absmax unchanged)
__global__ __launch_bounds__(256, 4) void fused_kernel(
    const int* __restrict__ atom_index, const float* __restrict__ shifts,
    const float* __restrict__ cart, const int* __restrict__ species,
    const float* __restrict__ rs, const float* __restrict__ inta,
    const float* __restrict__ params,
    int* __restrict__ cursors, nfloat4* __restrict__ records,
    float* __restrict__ out)
{
    cg::grid_group grid = cg::this_grid();

    __shared__ float s_rs[NTYPE * NWAVE];
    __shared__ float s_ia[NTYPE * NWAVE];
    __shared__ float s_pm[NTYPE * NWAVE];
    if (threadIdx.x < NTYPE * NWAVE) {
        s_rs[threadIdx.x] = rs[threadIdx.x];
        s_ia[threadIdx.x] = inta[threadIdx.x];
        s_pm[threadIdx.x] = params[threadIdx.x];
    }

    // ---- phase 0: zero cursors (blocks 0..7; 2048 int4 = 8192 ints) ----
    if (blockIdx.x < 8) {
        ((int4*)cursors)[blockIdx.x * 256 + threadIdx.x] = make_int4(0, 0, 0, 0);
    }
    grid.sync();

    // ---- phase 1: scatter (2 pairs/thread, coalesced halves) ----
    int tid = blockIdx.x * 256 + threadIdx.x;      // 262144 threads
#pragma unroll
    for (int h = 0; h < 2; ++h) {
        int gid = tid + h * (NPAIR / 2);
        float s0 = shifts[gid * 3 + 0];
        float s1 = shifts[gid * 3 + 1];
        float s2 = shifts[gid * 3 + 2];
        if (!(s0 > -1e10f && s1 > -1e10f && s2 > -1e10f)) continue;
        int b  = gid >> 15;                        // PPM = 2^15
        int i0 = atom_index[gid] + b * NATOM;
        int i1 = atom_index[NPAIR + gid] + b * NATOM;
        int pos = atomicAdd(&cursors[i0], 1);
        if (pos >= MAXN) continue;                 // safety clamp (never hit here)
        nfloat4 r;
        r.x = cart[i1 * 3 + 0] - s0;
        r.y = cart[i1 * 3 + 1] - s1;
        r.z = cart[i1 * 3 + 2] - s2;
        r.w = __int_as_float(species[i1]);
        records[i0 * MAXN + pos] = r;
    }
    grid.sync();

    // ---- phase 2: density (2 atoms per wave) ----
    int lane = threadIdx.x & 63;
    int w    = lane & 7;        // basis index
    int rsub = lane >> 3;       // record subset 0..7

#pragma unroll
    for (int a = 0; a < 2; ++a) {
        int atom = blockIdx.x * 8 + (threadIdx.x >> 6) + a * 4;

        int n = cursors[atom];
        if (n > MAXN) n = MAXN;
        const nfloat4* rec = records + (size_t)atom * MAXN;

        float cx = cart[atom * 3 + 0];
        float cy = cart[atom * 3 + 1];
        float cz = cart[atom * 3 + 2];

        float a0 = 0.f, a1 = 0.f, a2 = 0.f, a3 = 0.f, a4 = 0.f;
        float a5 = 0.f, a6 = 0.f, a7 = 0.f, a8 = 0.f, a9 = 0.f;

        for (int k = rsub; k < n; k += 8) {
            nfloat4 r = rec[k];                  // lanes 0-7 broadcast; wave = 128B line
            float dx = cx - r.x, dy = cy - r.y, dz = cz - r.z;
            int sp = __float_as_int(r.w);
            float d2 = dx * dx + dy * dy + dz * dz;
            float d  = sqrtf(d2);
            // fc = (0.5*cos(d*pi/5)+0.5)^2; v_cos_f32 takes revolutions:
            // cos(d*pi/5) = cos(2*pi*(d/10))
            float c  = 0.5f * __builtin_amdgcn_cosf(d * 0.1f) + 0.5f;
            float fc = c * c;
            int ti = sp * NWAVE + w;
            float t = d - s_rs[ti];
            float g = fc * s_pm[ti] * __expf(-s_ia[ti] * t * t);  // v_exp_f32
            a0 += g;
            a1 += g * dx; a2 += g * dy; a3 += g * dz;
            a4 += g * dx * dx; a5 += g * dx * dy; a6 += g * dx * dz;
            a7 += g * dy * dy; a8 += g * dy * dz; a9 += g * dz * dz;
        }

#define RED(v) { v += __shfl_xor(v, 8); v += __shfl_xor(v, 16); v += __shfl_xor(v, 32); }
        RED(a0) RED(a1) RED(a2) RED(a3) RED(a4)
        RED(a5) RED(a6) RED(a7) RED(a8) RED(a9)
#undef RED

        if (rsub == 0) {
            float* o = out + (size_t)atom * 24;
            o[w]      = a0 * a0;
            o[8 + w]  = a1 * a1 + a2 * a2 + a3 * a3;
            o[16 + w] = a4 * a4 + a7 * a7 + a9 * a9
                      + 2.0f * (a5 * a5 + a6 * a6 + a8 * a8);
        }
    }
}

extern "C" void kernel_launch(void* const* d_in, const int* in_sizes, int n_in,
                              void* d_out, int out_size, void* d_ws, size_t ws_size,
                              hipStream_t stream)
{
    const int*   atom_index= (const int*)d_in[3];
    const float* shifts    = (const float*)d_in[4];
    const float* cart      = (const float*)d_in[0];
    const int*   species   = (const int*)d_in[2];
    const float* rs        = (const float*)d_in[5];
    const float* inta      = (const float*)d_in[6];
    const float* params    = (const float*)d_in[7];
    float* out = (float*)d_out;

    char* ws = (char*)d_ws;
    int*     cursors = (int*)ws;
    nfloat4* records = (nfloat4*)(ws + WS_OFF_RECORDS);

    void* args[] = {
        (void*)&atom_index, (void*)&shifts, (void*)&cart, (void*)&species,
        (void*)&rs, (void*)&inta, (void*)&params,
        (void*)&cursors, (void*)&records, (void*)&out
    };
    hipLaunchCooperativeKernel((const void*)fused_kernel,
                               dim3(1024), dim3(256), args, 0, stream);
}

// Round 8
// 37.998 us; speedup vs baseline: 5.8482x; 5.8482x over previous
//
#include <hip/hip_runtime.h>
#include <math.h>

#define NBATCH 16
#define NATOM  512
#define NEIGH  64
#define PPM    (NATOM * NEIGH)      // 32768 = 2^15
#define NPAIR  (NBATCH * PPM)       // 524288
#define TOTATOM (NBATCH * NATOM)    // 8192
#define NTYPE  4
#define NWAVE  8
#define MAXN   128                  // slot capacity per atom (avg 64; Poisson tail safe at 128)

typedef float nfloat4 __attribute__((ext_vector_type(4)));

// ---- workspace layout (bytes) ----
// cursors : int[8192]                      @ 0        (32 KB)
// records : float4[TOTATOM * MAXN] (16 MB) @ 32768
#define WS_OFF_RECORDS 32768

// Measured decisions (kept):
//  - 3 separate dispatches; cooperative grid.sync fusion cost ~100us/sync (R7: 209us kernel)
//  - plain stores (nt regressed ~4us, R3/R4: random 16B stores must L2-merge)
//  - no XCD swizzle (regressed ~4.5us, R5)
//  - native v_cos_f32/v_exp_f32 (won ~1us, R6; absmax unchanged)

// Zero per-atom cursors (custom kernel: hipMemsetAsync node cost ~40 us in round 0).
__global__ __launch_bounds__(256) void zero_kernel(int4* __restrict__ cursors4)
{
    int gid = blockIdx.x * 256 + threadIdx.x;   // grid = 8 blocks -> 2048 int4 = 8192 ints
    cursors4[gid] = make_int4(0, 0, 0, 0);
}

// Scatter, 4 pairs/thread with vectorized loads:
//  - shifts: 3 x float4 = 48B contiguous per thread (aligned: 48*tid)
//  - atom_index: int4 per half (NPAIR multiple of 4)
//  - 4 independent atomic->store chains per thread (MLP for latency hiding)
__global__ __launch_bounds__(256) void scatter_kernel(
    const int* __restrict__ atom_index, const float* __restrict__ shifts,
    const float* __restrict__ cart, const int* __restrict__ species,
    int* __restrict__ cursors, nfloat4* __restrict__ records)
{
    int tid  = blockIdx.x * 256 + threadIdx.x;   // grid = 512 blocks -> 131072 threads
    int gid4 = tid * 4;                          // first of 4 consecutive pairs

    const nfloat4* sh4 = (const nfloat4*)(shifts + (size_t)gid4 * 3);
    nfloat4 sA = sh4[0];   // s0x s0y s0z s1x
    nfloat4 sB = sh4[1];   // s1y s1z s2x s2y
    nfloat4 sC = sh4[2];   // s2z s3x s3y s3z

    int4 ai0 = *(const int4*)(atom_index + gid4);
    int4 ai1 = *(const int4*)(atom_index + NPAIR + gid4);

    int b = gid4 >> 15;                          // PPM = 2^15; 4-pair group never crosses batch

    float sx[4] = { sA.x, sA.w, sB.z, sC.y };
    float sy[4] = { sA.y, sB.x, sB.w, sC.z };
    float sz[4] = { sA.z, sB.y, sC.x, sC.w };
    int   a0[4] = { ai0.x, ai0.y, ai0.z, ai0.w };
    int   a1[4] = { ai1.x, ai1.y, ai1.z, ai1.w };

#pragma unroll
    for (int h = 0; h < 4; ++h) {
        if (!(sx[h] > -1e10f && sy[h] > -1e10f && sz[h] > -1e10f)) continue;
        int i0 = a0[h] + b * NATOM;
        int i1 = a1[h] + b * NATOM;
        int pos = atomicAdd(&cursors[i0], 1);
        if (pos >= MAXN) continue;               // safety clamp (never hit here)
        nfloat4 r;
        r.x = cart[i1 * 3 + 0] - sx[h];
        r.y = cart[i1 * 3 + 1] - sy[h];
        r.z = cart[i1 * 3 + 2] - sz[h];
        r.w = __int_as_float(species[i1]);
        records[i0 * MAXN + pos] = r;
    }
}

__global__ __launch_bounds__(256) void density_kernel(
    const nfloat4* __restrict__ records, const int* __restrict__ cursors,
    const float* __restrict__ cart,
    const float* __restrict__ rs, const float* __restrict__ inta,
    const float* __restrict__ params, float* __restrict__ out)
{
    __shared__ float s_rs[NTYPE * NWAVE];
    __shared__ float s_ia[NTYPE * NWAVE];
    __shared__ float s_pm[NTYPE * NWAVE];
    if (threadIdx.x < NTYPE * NWAVE) {
        s_rs[threadIdx.x] = rs[threadIdx.x];
        s_ia[threadIdx.x] = inta[threadIdx.x];
        s_pm[threadIdx.x] = params[threadIdx.x];
    }
    __syncthreads();

    int atom = blockIdx.x * 4 + (threadIdx.x >> 6);  // grid = TOTATOM/4 = 2048
    int lane = threadIdx.x & 63;
    int w    = lane & 7;        // basis index
    int rsub = lane >> 3;       // record subset 0..7

    int n = cursors[atom];
    if (n > MAXN) n = MAXN;
    const nfloat4* rec = records + (size_t)atom * MAXN;

    float cx = cart[atom * 3 + 0];
    float cy = cart[atom * 3 + 1];
    float cz = cart[atom * 3 + 2];

    float a0 = 0.f, a1 = 0.f, a2 = 0.f, a3 = 0.f, a4 = 0.f;
    float a5 = 0.f, a6 = 0.f, a7 = 0.f, a8 = 0.f, a9 = 0.f;

    for (int k = rsub; k < n; k += 8) {
        nfloat4 r = rec[k];                      // lanes 0-7 broadcast; wave = 128B line
        float dx = cx - r.x, dy = cy - r.y, dz = cz - r.z;
        int sp = __float_as_int(r.w);
        float d2 = dx * dx + dy * dy + dz * dz;
        float d  = sqrtf(d2);
        // fc = (0.5*cos(d*pi/5)+0.5)^2; v_cos_f32 takes revolutions:
        // cos(d*pi/5) = cos(2*pi*(d/10))
        float c  = 0.5f * __builtin_amdgcn_cosf(d * 0.1f) + 0.5f;
        float fc = c * c;
        int ti = sp * NWAVE + w;
        float t = d - s_rs[ti];
        float g = fc * s_pm[ti] * __expf(-s_ia[ti] * t * t);   // v_exp_f32 pipe
        a0 += g;
        a1 += g * dx; a2 += g * dy; a3 += g * dz;
        a4 += g * dx * dx; a5 += g * dx * dy; a6 += g * dx * dz;
        a7 += g * dy * dy; a8 += g * dy * dz; a9 += g * dz * dz;
    }

#define RED(v) { v += __shfl_xor(v, 8); v += __shfl_xor(v, 16); v += __shfl_xor(v, 32); }
    RED(a0) RED(a1) RED(a2) RED(a3) RED(a4)
    RED(a5) RED(a6) RED(a7) RED(a8) RED(a9)
#undef RED

    if (rsub == 0) {
        float* o = out + (size_t)atom * 24;
        o[w]      = a0 * a0;
        o[8 + w]  = a1 * a1 + a2 * a2 + a3 * a3;
        o[16 + w] = a4 * a4 + a7 * a7 + a9 * a9
                  + 2.0f * (a5 * a5 + a6 * a6 + a8 * a8);
    }
}

extern "C" void kernel_launch(void* const* d_in, const int* in_sizes, int n_in,
                              void* d_out, int out_size, void* d_ws, size_t ws_size,
                              hipStream_t stream)
{
    const float* cart      = (const float*)d_in[0];
    // d_in[1] = numatoms (unused by reference math)
    const int*   species   = (const int*)d_in[2];
    const int*   atom_index= (const int*)d_in[3];
    const float* shifts    = (const float*)d_in[4];
    const float* rs        = (const float*)d_in[5];
    const float* inta      = (const float*)d_in[6];
    const float* params    = (const float*)d_in[7];
    float* out = (float*)d_out;

    char* ws = (char*)d_ws;
    int*     cursors = (int*)ws;
    nfloat4* records = (nfloat4*)(ws + WS_OFF_RECORDS);

    zero_kernel<<<TOTATOM / 1024, 256, 0, stream>>>((int4*)cursors);
    scatter_kernel<<<NPAIR / 1024, 256, 0, stream>>>(
        atom_index, shifts, cart, species, cursors, records);
    density_kernel<<<TOTATOM / 4, 256, 0, stream>>>(
        records, cursors, cart, rs, inta, params, out);
}

// Round 9
// 37.416 us; speedup vs baseline: 5.9392x; 1.0156x over previous
//
#include <hip/hip_runtime.h>
#include <math.h>

#define NBATCH 16
#define NATOM  512
#define NEIGH  64
#define PPM    (NATOM * NEIGH)      // 32768 = 2^15
#define NPAIR  (NBATCH * PPM)       // 524288
#define TOTATOM (NBATCH * NATOM)    // 8192
#define NTYPE  4
#define NWAVE  8
#define MAXN   128                  // slot capacity per atom (avg 64; Poisson tail safe at 128)

typedef float nfloat4 __attribute__((ext_vector_type(4)));

// ---- workspace layout (bytes) ----
// cursors : int[8192]                      @ 0        (32 KB)
// records : float4[TOTATOM * MAXN] (16 MB) @ 32768
#define WS_OFF_RECORDS 32768

// Measured decisions (kept):
//  - 3 separate dispatches; cooperative grid.sync fusion cost ~100us/sync (R7: 209us)
//  - plain stores (nt regressed ~4us, R3/R4: random 16B stores must L2-merge)
//  - no XCD swizzle (regressed ~4.5us, R5)
//  - native v_cos_f32/v_exp_f32 (won ~1us, R6; absmax unchanged)
//  - scatter MLP: 1->4 chains/thread won ~13us (R8) — scatter was the
//    latency-chain-bound dominant kernel, hidden below the top-5 cutoff.

// Zero per-atom cursors (custom kernel: hipMemsetAsync node cost ~40 us in round 0).
__global__ __launch_bounds__(256) void zero_kernel(int4* __restrict__ cursors4)
{
    int gid = blockIdx.x * 256 + threadIdx.x;   // grid = 8 blocks -> 2048 int4 = 8192 ints
    cursors4[gid] = make_int4(0, 0, 0, 0);
}

// Scatter, 8 pairs/thread (R9 probe: marginal return of deeper MLP):
//  - shifts: 6 x float4 = 96B contiguous per thread (aligned: 96*tid)
//  - atom_index: 2 x int4 per endpoint array
//  - 8 independent atomic->store chains per thread
__global__ __launch_bounds__(256) void scatter_kernel(
    const int* __restrict__ atom_index, const float* __restrict__ shifts,
    const float* __restrict__ cart, const int* __restrict__ species,
    int* __restrict__ cursors, nfloat4* __restrict__ records)
{
    int tid  = blockIdx.x * 256 + threadIdx.x;   // grid = 256 blocks -> 65536 threads
    int gid8 = tid * 8;                          // first of 8 consecutive pairs

    const nfloat4* sh4 = (const nfloat4*)(shifts + (size_t)gid8 * 3);
    nfloat4 S0 = sh4[0], S1 = sh4[1], S2 = sh4[2];
    nfloat4 S3 = sh4[3], S4 = sh4[4], S5 = sh4[5];
    float f[24] = { S0.x,S0.y,S0.z,S0.w, S1.x,S1.y,S1.z,S1.w,
                    S2.x,S2.y,S2.z,S2.w, S3.x,S3.y,S3.z,S3.w,
                    S4.x,S4.y,S4.z,S4.w, S5.x,S5.y,S5.z,S5.w };

    int4 A0 = *(const int4*)(atom_index + gid8);
    int4 A1 = *(const int4*)(atom_index + gid8 + 4);
    int4 B0 = *(const int4*)(atom_index + NPAIR + gid8);
    int4 B1 = *(const int4*)(atom_index + NPAIR + gid8 + 4);
    int a0[8] = { A0.x, A0.y, A0.z, A0.w, A1.x, A1.y, A1.z, A1.w };
    int a1[8] = { B0.x, B0.y, B0.z, B0.w, B1.x, B1.y, B1.z, B1.w };

    int b = gid8 >> 15;                          // PPM = 2^15; 8-pair group never crosses batch

#pragma unroll
    for (int h = 0; h < 8; ++h) {                // constant indices after unroll -> registers
        float sx = f[3 * h], sy = f[3 * h + 1], sz = f[3 * h + 2];
        if (!(sx > -1e10f && sy > -1e10f && sz > -1e10f)) continue;
        int i0 = a0[h] + b * NATOM;
        int i1 = a1[h] + b * NATOM;
        int pos = atomicAdd(&cursors[i0], 1);
        if (pos >= MAXN) continue;               // safety clamp (never hit here)
        nfloat4 r;
        r.x = cart[i1 * 3 + 0] - sx;
        r.y = cart[i1 * 3 + 1] - sy;
        r.z = cart[i1 * 3 + 2] - sz;
        r.w = __int_as_float(species[i1]);
        records[i0 * MAXN + pos] = r;
    }
}

__global__ __launch_bounds__(256) void density_kernel(
    const nfloat4* __restrict__ records, const int* __restrict__ cursors,
    const float* __restrict__ cart,
    const float* __restrict__ rs, const float* __restrict__ inta,
    const float* __restrict__ params, float* __restrict__ out)
{
    __shared__ float s_rs[NTYPE * NWAVE];
    __shared__ float s_ia[NTYPE * NWAVE];
    __shared__ float s_pm[NTYPE * NWAVE];
    if (threadIdx.x < NTYPE * NWAVE) {
        s_rs[threadIdx.x] = rs[threadIdx.x];
        s_ia[threadIdx.x] = inta[threadIdx.x];
        s_pm[threadIdx.x] = params[threadIdx.x];
    }
    __syncthreads();

    int atom = blockIdx.x * 4 + (threadIdx.x >> 6);  // grid = TOTATOM/4 = 2048
    int lane = threadIdx.x & 63;
    int w    = lane & 7;        // basis index
    int rsub = lane >> 3;       // record subset 0..7

    int n = cursors[atom];
    if (n > MAXN) n = MAXN;
    const nfloat4* rec = records + (size_t)atom * MAXN;

    float cx = cart[atom * 3 + 0];
    float cy = cart[atom * 3 + 1];
    float cz = cart[atom * 3 + 2];

    float a0 = 0.f, a1 = 0.f, a2 = 0.f, a3 = 0.f, a4 = 0.f;
    float a5 = 0.f, a6 = 0.f, a7 = 0.f, a8 = 0.f, a9 = 0.f;

    for (int k = rsub; k < n; k += 8) {
        nfloat4 r = rec[k];                      // lanes 0-7 broadcast; wave = 128B line
        float dx = cx - r.x, dy = cy - r.y, dz = cz - r.z;
        int sp = __float_as_int(r.w);
        float d2 = dx * dx + dy * dy + dz * dz;
        float d  = sqrtf(d2);
        // fc = (0.5*cos(d*pi/5)+0.5)^2; v_cos_f32 takes revolutions:
        // cos(d*pi/5) = cos(2*pi*(d/10))
        float c  = 0.5f * __builtin_amdgcn_cosf(d * 0.1f) + 0.5f;
        float fc = c * c;
        int ti = sp * NWAVE + w;
        float t = d - s_rs[ti];
        float g = fc * s_pm[ti] * __expf(-s_ia[ti] * t * t);   // v_exp_f32 pipe
        a0 += g;
        a1 += g * dx; a2 += g * dy; a3 += g * dz;
        a4 += g * dx * dx; a5 += g * dx * dy; a6 += g * dx * dz;
        a7 += g * dy * dy; a8 += g * dy * dz; a9 += g * dz * dz;
    }

#define RED(v) { v += __shfl_xor(v, 8); v += __shfl_xor(v, 16); v += __shfl_xor(v, 32); }
    RED(a0) RED(a1) RED(a2) RED(a3) RED(a4)
    RED(a5) RED(a6) RED(a7) RED(a8) RED(a9)
#undef RED

    if (rsub == 0) {
        float* o = out + (size_t)atom * 24;
        o[w]      = a0 * a0;
        o[8 + w]  = a1 * a1 + a2 * a2 + a3 * a3;
        o[16 + w] = a4 * a4 + a7 * a7 + a9 * a9
                  + 2.0f * (a5 * a5 + a6 * a6 + a8 * a8);
    }
}

extern "C" void kernel_launch(void* const* d_in, const int* in_sizes, int n_in,
                              void* d_out, int out_size, void* d_ws, size_t ws_size,
                              hipStream_t stream)
{
    const float* cart      = (const float*)d_in[0];
    // d_in[1] = numatoms (unused by reference math)
    const int*   species   = (const int*)d_in[2];
    const int*   atom_index= (const int*)d_in[3];
    const float* shifts    = (const float*)d_in[4];
    const float* rs        = (const float*)d_in[5];
    const float* inta      = (const float*)d_in[6];
    const float* params    = (const float*)d_in[7];
    float* out = (float*)d_out;

    char* ws = (char*)d_ws;
    int*     cursors = (int*)ws;
    nfloat4* records = (nfloat4*)(ws + WS_OFF_RECORDS);

    zero_kernel<<<TOTATOM / 1024, 256, 0, stream>>>((int4*)cursors);
    scatter_kernel<<<NPAIR / 2048, 256, 0, stream>>>(
        atom_index, shifts, cart, species, cursors, records);
    density_kernel<<<TOTATOM / 4, 256, 0, stream>>>(
        records, cursors, cart, rs, inta, params, out);
}

// Round 10
// 35.867 us; speedup vs baseline: 6.1957x; 1.0432x over previous
//
#include <hip/hip_runtime.h>
#include <math.h>

#define NBATCH 16
#define NATOM  512
#define NEIGH  64
#define PPM    (NATOM * NEIGH)      // 32768 = 2^15
#define NPAIR  (NBATCH * PPM)       // 524288
#define TOTATOM (NBATCH * NATOM)    // 8192
#define NTYPE  4
#define NWAVE  8
#define MAXN   128                  // slot capacity per atom (avg 64; Poisson tail safe at 128)

typedef float nfloat4 __attribute__((ext_vector_type(4)));

// ---- workspace layout (bytes) ----
// cursors : int[8192]                      @ 0        (32 KB)
// records : float4[TOTATOM * MAXN] (16 MB) @ 32768
#define WS_OFF_RECORDS 32768

// Measured decisions (kept):
//  - 3 separate dispatches; cooperative grid.sync fusion cost ~100us/sync (R7: 209us)
//  - plain stores (nt regressed ~4us, R3/R4: random 16B stores must L2-merge)
//  - no XCD swizzle (regressed ~4.5us, R5)
//  - native v_cos_f32/v_exp_f32 (won ~1us, R6; absmax unchanged)
//  - scatter MLP: 1->4 chains/thread won ~13us (R8); 4->8 flat (R9) -> scatter at floor
//  - R7 counters: FETCH == input footprint exactly -> no write-allocate fetch
//    amplification; WRITE ~2-3x amplified (~3us) -> traffic is NOT the 20us.

// Zero per-atom cursors (custom kernel: hipMemsetAsync node cost ~40 us in round 0).
__global__ __launch_bounds__(256) void zero_kernel(int4* __restrict__ cursors4)
{
    int gid = blockIdx.x * 256 + threadIdx.x;   // grid = 8 blocks -> 2048 int4 = 8192 ints
    cursors4[gid] = make_int4(0, 0, 0, 0);
}

// Scatter, 8 pairs/thread (R9 config — best measured, kept unchanged).
__global__ __launch_bounds__(256) void scatter_kernel(
    const int* __restrict__ atom_index, const float* __restrict__ shifts,
    const float* __restrict__ cart, const int* __restrict__ species,
    int* __restrict__ cursors, nfloat4* __restrict__ records)
{
    int tid  = blockIdx.x * 256 + threadIdx.x;   // grid = 256 blocks -> 65536 threads
    int gid8 = tid * 8;                          // first of 8 consecutive pairs

    const nfloat4* sh4 = (const nfloat4*)(shifts + (size_t)gid8 * 3);
    nfloat4 S0 = sh4[0], S1 = sh4[1], S2 = sh4[2];
    nfloat4 S3 = sh4[3], S4 = sh4[4], S5 = sh4[5];
    float f[24] = { S0.x,S0.y,S0.z,S0.w, S1.x,S1.y,S1.z,S1.w,
                    S2.x,S2.y,S2.z,S2.w, S3.x,S3.y,S3.z,S3.w,
                    S4.x,S4.y,S4.z,S4.w, S5.x,S5.y,S5.z,S5.w };

    int4 A0 = *(const int4*)(atom_index + gid8);
    int4 A1 = *(const int4*)(atom_index + gid8 + 4);
    int4 B0 = *(const int4*)(atom_index + NPAIR + gid8);
    int4 B1 = *(const int4*)(atom_index + NPAIR + gid8 + 4);
    int a0[8] = { A0.x, A0.y, A0.z, A0.w, A1.x, A1.y, A1.z, A1.w };
    int a1[8] = { B0.x, B0.y, B0.z, B0.w, B1.x, B1.y, B1.z, B1.w };

    int b = gid8 >> 15;                          // PPM = 2^15; 8-pair group never crosses batch

#pragma unroll
    for (int h = 0; h < 8; ++h) {                // constant indices after unroll -> registers
        float sx = f[3 * h], sy = f[3 * h + 1], sz = f[3 * h + 2];
        if (!(sx > -1e10f && sy > -1e10f && sz > -1e10f)) continue;
        int i0 = a0[h] + b * NATOM;
        int i1 = a1[h] + b * NATOM;
        int pos = atomicAdd(&cursors[i0], 1);
        if (pos >= MAXN) continue;               // safety clamp (never hit here)
        nfloat4 r;
        r.x = cart[i1 * 3 + 0] - sx;
        r.y = cart[i1 * 3 + 1] - sy;
        r.z = cart[i1 * 3 + 2] - sz;
        r.w = __int_as_float(species[i1]);
        records[i0 * MAXN + pos] = r;
    }
}

// Density: R10 change — process TWO records per loop iteration (k += 16),
// both loads issued before compute (2x load-level parallelism per wave,
// half the latency-exposed loop boundaries). n/cart loads hoisted above
// the barrier to overlap with the LDS fill.
__global__ __launch_bounds__(256) void density_kernel(
    const nfloat4* __restrict__ records, const int* __restrict__ cursors,
    const float* __restrict__ cart,
    const float* __restrict__ rs, const float* __restrict__ inta,
    const float* __restrict__ params, float* __restrict__ out)
{
    __shared__ float s_rs[NTYPE * NWAVE];
    __shared__ float s_ia[NTYPE * NWAVE];
    __shared__ float s_pm[NTYPE * NWAVE];

    int atom = blockIdx.x * 4 + (threadIdx.x >> 6);  // grid = TOTATOM/4 = 2048
    int lane = threadIdx.x & 63;
    int w    = lane & 7;        // basis index
    int rsub = lane >> 3;       // record subset 0..7

    // issue global loads BEFORE the barrier so they overlap the LDS fill
    int n = cursors[atom];
    float cx = cart[atom * 3 + 0];
    float cy = cart[atom * 3 + 1];
    float cz = cart[atom * 3 + 2];

    if (threadIdx.x < NTYPE * NWAVE) {
        s_rs[threadIdx.x] = rs[threadIdx.x];
        s_ia[threadIdx.x] = inta[threadIdx.x];
        s_pm[threadIdx.x] = params[threadIdx.x];
    }
    __syncthreads();

    if (n > MAXN) n = MAXN;
    const nfloat4* rec = records + (size_t)atom * MAXN;

    float a0 = 0.f, a1 = 0.f, a2 = 0.f, a3 = 0.f, a4 = 0.f;
    float a5 = 0.f, a6 = 0.f, a7 = 0.f, a8 = 0.f, a9 = 0.f;

#define BODY(RV)                                                          \
    {                                                                     \
        float dx = cx - RV.x, dy = cy - RV.y, dz = cz - RV.z;             \
        int sp = __float_as_int(RV.w);                                    \
        float d2 = dx * dx + dy * dy + dz * dz;                           \
        float d  = sqrtf(d2);                                             \
        float c  = 0.5f * __builtin_amdgcn_cosf(d * 0.1f) + 0.5f;         \
        float fc = c * c;                                                 \
        int ti = sp * NWAVE + w;                                          \
        float t = d - s_rs[ti];                                           \
        float g = fc * s_pm[ti] * __expf(-s_ia[ti] * t * t);              \
        a0 += g;                                                          \
        a1 += g * dx; a2 += g * dy; a3 += g * dz;                         \
        a4 += g * dx * dx; a5 += g * dx * dy; a6 += g * dx * dz;          \
        a7 += g * dy * dy; a8 += g * dy * dz; a9 += g * dz * dz;          \
    }

    int k = rsub;
    for (; k + 8 < n; k += 16) {
        nfloat4 r1 = rec[k];        // two independent 128B wave-lines in flight
        nfloat4 r2 = rec[k + 8];
        BODY(r1)
        BODY(r2)
    }
    if (k < n) {
        nfloat4 r1 = rec[k];
        BODY(r1)
    }
#undef BODY

#define RED(v) { v += __shfl_xor(v, 8); v += __shfl_xor(v, 16); v += __shfl_xor(v, 32); }
    RED(a0) RED(a1) RED(a2) RED(a3) RED(a4)
    RED(a5) RED(a6) RED(a7) RED(a8) RED(a9)
#undef RED

    if (rsub == 0) {
        float* o = out + (size_t)atom * 24;
        o[w]      = a0 * a0;
        o[8 + w]  = a1 * a1 + a2 * a2 + a3 * a3;
        o[16 + w] = a4 * a4 + a7 * a7 + a9 * a9
                  + 2.0f * (a5 * a5 + a6 * a6 + a8 * a8);
    }
}

extern "C" void kernel_launch(void* const* d_in, const int* in_sizes, int n_in,
                              void* d_out, int out_size, void* d_ws, size_t ws_size,
                              hipStream_t stream)
{
    const float* cart      = (const float*)d_in[0];
    // d_in[1] = numatoms (unused by reference math)
    const int*   species   = (const int*)d_in[2];
    const int*   atom_index= (const int*)d_in[3];
    const float* shifts    = (const float*)d_in[4];
    const float* rs        = (const float*)d_in[5];
    const float* inta      = (const float*)d_in[6];
    const float* params    = (const float*)d_in[7];
    float* out = (float*)d_out;

    char* ws = (char*)d_ws;
    int*     cursors = (int*)ws;
    nfloat4* records = (nfloat4*)(ws + WS_OFF_RECORDS);

    zero_kernel<<<TOTATOM / 1024, 256, 0, stream>>>((int4*)cursors);
    scatter_kernel<<<NPAIR / 2048, 256, 0, stream>>>(
        atom_index, shifts, cart, species, cursors, records);
    density_kernel<<<TOTATOM / 4, 256, 0, stream>>>(
        records, cursors, cart, rs, inta, params, out);
}